// Round 3
// baseline (205.628 us; speedup 1.0000x reference)
//
#include <hip/hip_runtime.h>
#include <math.h>

#define N_G   64
#define M_N   32
#define FEAT  256
#define POSD  6
#define D     262
#define MSG   128
#define NCLS  7

#define KA_S  424       // LDS buf row stride (shorts): 416 data + 8 pad (bank-conflict-free)
#define KHW   288       // weight K window over h (262 -> 288)
#define KFULL 416       // full concat K: [mv 128 | h 262 | pad]

// packed weight sizes (shorts)
#define S_PROJ (528*288)
#define S_MSG  (128*288)
#define S_RZ   (544*416)
#define S_XN   (272*128)
#define S_HN   (272*288)
#define S_RO   (128*288)
#define S_RO2  (16*128)

// workspace float offsets
#define O_WPROJ 0u
#define O_WMSG  76032u
#define O_WRZ   94464u
#define O_WXN   207616u
#define O_WHN   225024u
#define O_WRO   264192u
#define O_WRO2  282624u
#define O_GB    283648u   // 1088 fp32 gate biases [br|bz|bxn|bhn] x 272

typedef __attribute__((ext_vector_type(8))) short short8;
typedef __attribute__((ext_vector_type(4))) float floatx4;

#define MFMA __builtin_amdgcn_mfma_f32_16x16x32_bf16

__device__ __forceinline__ short f2bf(float f) {
    union { float f; unsigned u; } v; v.f = f;
    unsigned r = v.u + 0x7FFF + ((v.u >> 16) & 1);   // RNE
    return (short)(r >> 16);
}
__device__ __forceinline__ float bf2f(short s) {
    union { float f; unsigned u; } v;
    v.u = ((unsigned)(unsigned short)s) << 16;
    return v.f;
}
__device__ __forceinline__ float sigf(float x) { return 1.f / (1.f + expf(-x)); }

// ---------------------------------------------------------------------------
// prep: pack all weights bf16 [n][k] (B^T) with padded/zeroed windows + biases
// ---------------------------------------------------------------------------
__global__ void prep_kernel(const float* __restrict__ w1, const float* __restrict__ msg_w,
                            const float* __restrict__ w_ih, const float* __restrict__ w_hh,
                            const float* __restrict__ ro_w1, const float* __restrict__ ro_w2,
                            const float* __restrict__ b_ih, const float* __restrict__ b_hh,
                            float* __restrict__ ws)
{
    short* wproj = (short*)(ws + O_WPROJ);
    short* wmsg  = (short*)(ws + O_WMSG);
    short* wrz   = (short*)(ws + O_WRZ);
    short* wxn   = (short*)(ws + O_WXN);
    short* whn   = (short*)(ws + O_WHN);
    short* wro   = (short*)(ws + O_WRO);
    short* wro2  = (short*)(ws + O_WRO2);
    float* gb    = ws + O_GB;
    const int TOT_S = S_PROJ + S_MSG + S_RZ + S_XN + S_HN + S_RO + S_RO2;
    const int TOTAL = TOT_S + 1088;
    for (int i = blockIdx.x * blockDim.x + threadIdx.x; i < TOTAL;
         i += gridDim.x * blockDim.x) {
        int idx = i;
        if (idx < S_PROJ) {                       // [528][288]
            int n = idx / 288, k = idx % 288;
            float v = 0.f;
            if (k < D && n < 524)
                v = (n < D) ? w1[n * 524 + k] : w1[(n - D) * 524 + D + k];
            wproj[idx] = f2bf(v);
            continue;
        }
        idx -= S_PROJ;
        if (idx < S_MSG) {                        // [128][288]
            int n = idx / 288, k = idx % 288;
            wmsg[idx] = f2bf(k < D ? msg_w[n * D + k] : 0.f);
            continue;
        }
        idx -= S_MSG;
        if (idx < S_RZ) {                         // [544][416]: rows 0..271 r, 272..543 z
            int g = idx / 416, k = idx % 416;
            int gi = (g < 272) ? 0 : 1;
            int d = g - gi * 272;
            float v = 0.f;
            if (d < D) {
                int row = gi * D + d;
                if (k < 128)            v = w_ih[row * MSG + k];
                else if (k < 128 + D)   v = w_hh[row * D + (k - 128)];
            }
            wrz[idx] = f2bf(v);
            continue;
        }
        idx -= S_RZ;
        if (idx < S_XN) {                         // [272][128]
            int d = idx / 128, k = idx % 128;
            wxn[idx] = f2bf(d < D ? w_ih[(2 * D + d) * MSG + k] : 0.f);
            continue;
        }
        idx -= S_XN;
        if (idx < S_HN) {                         // [272][288]
            int d = idx / 288, k = idx % 288;
            whn[idx] = f2bf((d < D && k < D) ? w_hh[(2 * D + d) * D + k] : 0.f);
            continue;
        }
        idx -= S_HN;
        if (idx < S_RO) {                         // [128][288]
            int n = idx / 288, k = idx % 288;
            wro[idx] = f2bf(k < D ? ro_w1[n * D + k] : 0.f);
            continue;
        }
        idx -= S_RO;
        if (idx < S_RO2) {                        // [16][128]
            int n = idx / 128, k = idx % 128;
            wro2[idx] = f2bf(n < NCLS ? ro_w2[n * MSG + k] : 0.f);
            continue;
        }
        idx -= S_RO2;
        {                                          // gate biases [4][272]
            int seg = idx / 272, d = idx % 272;
            float v = 0.f;
            if (d < D) {
                if (seg == 0)      v = b_ih[d] + b_hh[d];
                else if (seg == 1) v = b_ih[D + d] + b_hh[D + d];
                else if (seg == 2) v = b_ih[2 * D + d];
                else               v = b_hh[2 * D + d];
            }
            gb[idx] = v;
        }
    }
}

// ---------------------------------------------------------------------------
// fused: one block per graph; full forward in LDS
// ---------------------------------------------------------------------------
__global__ __launch_bounds__(512, 2) void fused_kernel(
    const float* __restrict__ nodes, const float* __restrict__ pos,
    const int* __restrict__ nrec_g,
    const float* __restrict__ b1g, const float* __restrict__ w2g,
    const float* __restrict__ b2g, const float* __restrict__ msg_bg,
    const float* __restrict__ ro_b1g, const float* __restrict__ ro_b2g,
    const float* __restrict__ ws,
    float* __restrict__ att_out, float* __restrict__ pred)
{
    const short* Wproj = (const short*)(ws + O_WPROJ);
    const short* Wmsg  = (const short*)(ws + O_WMSG);
    const short* Wrz   = (const short*)(ws + O_WRZ);
    const short* Wxn   = (const short*)(ws + O_WXN);
    const short* Whn   = (const short*)(ws + O_WHN);
    const short* Wro   = (const short*)(ws + O_WRO);
    const short* Wro2  = (const short*)(ws + O_WRO2);
    const float* gb    = ws + O_GB;

    __shared__ __align__(16) short bufA[32 * KA_S];
    __shared__ __align__(16) short bufB[32 * KA_S];
    __shared__ __align__(16) float projL[32 * 532];
    __shared__ float attL[32 * 32];
    __shared__ float msgF[32 * 132];
    __shared__ __align__(16) short hidL[32 * 136];
    __shared__ float b1L[D], w2L[D];

    const int b = blockIdx.x;
    const int tid = threadIdx.x;
    const int wave = tid >> 6, lane = tid & 63;
    const int quad = lane >> 4, lrow = lane & 15;
    const int nr = nrec_g[b];

    // ---- P0: load h0, zero mv region + bufB ----
    for (int idx = tid; idx < 32 * 288; idx += 512) {
        int w = idx / 288, c = idx % 288;
        float v = 0.f;
        if (c < FEAT)      v = nodes[((size_t)(b * 32 + w)) * FEAT + c];
        else if (c < D)    v = pos[((size_t)(b * 32 + w)) * POSD + (c - FEAT)];
        bufA[w * KA_S + 128 + c] = f2bf(v);
    }
    for (int idx = tid; idx < 32 * 128; idx += 512) {
        int w = idx >> 7, c = idx & 127;
        bufA[w * KA_S + c] = 0;
    }
    for (int idx = tid; idx < 32 * KA_S; idx += 512) bufB[idx] = 0;
    for (int d = tid; d < D; d += 512) { b1L[d] = b1g[d]; w2L[d] = w2g[d]; }
    __syncthreads();

    // ---- P1: proj = h0 @ Wproj^T (528 cols) ----
    for (int s = wave; s < 33; s += 8) {
        floatx4 acc0 = {}, acc1 = {};
        const short* bw = Wproj + (s * 16 + lrow) * KHW + quad * 8;
        const short* ap = bufA + lrow * KA_S + 128 + quad * 8;
        for (int kk = 0; kk < 9; ++kk) {
            short8 a0 = *(const short8*)(ap + kk * 32);
            short8 a1 = *(const short8*)(ap + 16 * KA_S + kk * 32);
            short8 bv = *(const short8*)(bw + kk * 32);
            acc0 = MFMA(a0, bv, acc0, 0, 0, 0);
            acc1 = MFMA(a1, bv, acc1, 0, 0, 0);
        }
        int col = s * 16 + lrow;
#pragma unroll
        for (int rr = 0; rr < 4; ++rr) {
            projL[(quad * 4 + rr) * 532 + col] = acc0[rr];
            projL[(16 + quad * 4 + rr) * 532 + col] = acc1[rr];
        }
    }
    __syncthreads();

    // ---- P2: attention ----
    {
        const float b2v = b2g[0];
        int pp = tid >> 3, c8 = tid & 7;
        for (int it = 0; it < 16; ++it) {
            int p = pp + 64 * it;
            int i = p >> 5, j = p & 31;
            float sel = (i < nr && j < nr) ? 1.f : 0.f;
            const float* pa = projL + i * 532;
            const float* pb = projL + j * 532 + D;
            float sacc = 0.f;
            for (int d = c8; d < D; d += 8)
                sacc += fmaxf(sel * (pa[d] + pb[d]) + b1L[d], 0.f) * w2L[d];
            sacc += __shfl_down(sacc, 4, 8);
            sacc += __shfl_down(sacc, 2, 8);
            sacc += __shfl_down(sacc, 1, 8);
            if (c8 == 0) {
                float a = sigf(sacc + b2v);
                att_out[((size_t)(b * 32 + i)) * 32 + j] = a;
                attL[i * 32 + j] = (j < nr) ? a : 0.f;
            }
        }
    }
    __syncthreads();

    // ---- two message-passing rounds ----
    for (int rnd = 0; rnd < 2; ++rnd) {
        short* src = rnd ? bufB : bufA;
        short* dst = rnd ? bufA : bufB;

        // msg = h @ Wmsg^T + msg_b  -> msgF fp32
        {
            int s = wave;                         // 8 slices, 8 waves
            floatx4 acc0 = {}, acc1 = {};
            const short* bw = Wmsg + (s * 16 + lrow) * KHW + quad * 8;
            const short* ap = src + lrow * KA_S + 128 + quad * 8;
            for (int kk = 0; kk < 9; ++kk) {
                short8 a0 = *(const short8*)(ap + kk * 32);
                short8 a1 = *(const short8*)(ap + 16 * KA_S + kk * 32);
                short8 bv = *(const short8*)(bw + kk * 32);
                acc0 = MFMA(a0, bv, acc0, 0, 0, 0);
                acc1 = MFMA(a1, bv, acc1, 0, 0, 0);
            }
            int col = s * 16 + lrow;
            float bias = msg_bg[col];
#pragma unroll
            for (int rr = 0; rr < 4; ++rr) {
                msgF[(quad * 4 + rr) * 132 + col] = acc0[rr] + bias;
                msgF[(16 + quad * 4 + rr) * 132 + col] = acc1[rr] + bias;
            }
        }
        __syncthreads();

        // mix: mv = att @ msgF -> bf16 into src cols 0..128
        for (int idx = tid; idx < 32 * 128; idx += 512) {
            int m = idx >> 7, k = idx & 127;
            float acc = 0.f;
#pragma unroll
            for (int w = 0; w < 32; ++w)
                acc = fmaf(attL[m * 32 + w], msgF[w * 132 + k], acc);
            src[m * KA_S + k] = f2bf(acc);
        }
        __syncthreads();

        // GRU: fused [gx|gh] GEMM + elementwise, writes dst h-cols
        for (int s = wave; s < 17; s += 8) {
            floatx4 aR0 = {}, aR1 = {}, aZ0 = {}, aZ1 = {};
            floatx4 aN0 = {}, aN1 = {}, aH0 = {}, aH1 = {};
            const short* ap  = src + lrow * KA_S + quad * 8;
            const short* bpr = Wrz + (s * 16 + lrow) * KFULL + quad * 8;
            const short* bpz = Wrz + (272 + s * 16 + lrow) * KFULL + quad * 8;
            const short* bpx = Wxn + (s * 16 + lrow) * 128 + quad * 8;
            const short* bph = Whn + (s * 16 + lrow) * KHW + quad * 8;
            for (int kk = 0; kk < 13; ++kk) {
                short8 a0 = *(const short8*)(ap + kk * 32);
                short8 a1 = *(const short8*)(ap + 16 * KA_S + kk * 32);
                short8 br = *(const short8*)(bpr + kk * 32);
                short8 bz = *(const short8*)(bpz + kk * 32);
                aR0 = MFMA(a0, br, aR0, 0, 0, 0);
                aR1 = MFMA(a1, br, aR1, 0, 0, 0);
                aZ0 = MFMA(a0, bz, aZ0, 0, 0, 0);
                aZ1 = MFMA(a1, bz, aZ1, 0, 0, 0);
                if (kk < 4) {
                    short8 bx = *(const short8*)(bpx + kk * 32);
                    aN0 = MFMA(a0, bx, aN0, 0, 0, 0);
                    aN1 = MFMA(a1, bx, aN1, 0, 0, 0);
                } else {
                    short8 bh = *(const short8*)(bph + (kk - 4) * 32);
                    aH0 = MFMA(a0, bh, aH0, 0, 0, 0);
                    aH1 = MFMA(a1, bh, aH1, 0, 0, 0);
                }
            }
            int d = s * 16 + lrow;
            if (d < D) {
                float bgr = gb[d], bgz = gb[272 + d];
                float bxv = gb[544 + d], bhv = gb[816 + d];
#pragma unroll
                for (int i = 0; i < 2; ++i) {
                    floatx4 vR = i ? aR1 : aR0, vZ = i ? aZ1 : aZ0;
                    floatx4 vN = i ? aN1 : aN0, vH = i ? aH1 : aH0;
#pragma unroll
                    for (int rr = 0; rr < 4; ++rr) {
                        int m = i * 16 + quad * 4 + rr;
                        float rg = sigf(vR[rr] + bgr);
                        float zg = sigf(vZ[rr] + bgz);
                        float cg = tanhf(vN[rr] + bxv + rg * (vH[rr] + bhv));
                        float hold = bf2f(src[m * KA_S + 128 + d]);
                        float hv = (1.f - zg) * cg + zg * hold;
                        if (m >= nr) hv = 0.f;
                        dst[m * KA_S + 128 + d] = f2bf(hv);
                    }
                }
            }
        }
        __syncthreads();
    }

    // ---- readout: hid = relu(h2 @ Wro^T + ro_b1), h2 in bufA ----
    {
        int s = wave;
        floatx4 acc0 = {}, acc1 = {};
        const short* bw = Wro + (s * 16 + lrow) * KHW + quad * 8;
        const short* ap = bufA + lrow * KA_S + 128 + quad * 8;
        for (int kk = 0; kk < 9; ++kk) {
            short8 a0 = *(const short8*)(ap + kk * 32);
            short8 a1 = *(const short8*)(ap + 16 * KA_S + kk * 32);
            short8 bv = *(const short8*)(bw + kk * 32);
            acc0 = MFMA(a0, bv, acc0, 0, 0, 0);
            acc1 = MFMA(a1, bv, acc1, 0, 0, 0);
        }
        int col = s * 16 + lrow;
        float bias = ro_b1g[col];
#pragma unroll
        for (int rr = 0; rr < 4; ++rr) {
            hidL[(quad * 4 + rr) * 136 + col] = f2bf(fmaxf(acc0[rr] + bias, 0.f));
            hidL[(16 + quad * 4 + rr) * 136 + col] = f2bf(fmaxf(acc1[rr] + bias, 0.f));
        }
    }
    __syncthreads();

    // ---- final: pred = hid @ ro_w2^T + ro_b2 (wave 0 only) ----
    if (wave == 0) {
        floatx4 acc0 = {}, acc1 = {};
        const short* ap = hidL + lrow * 136 + quad * 8;
        const short* bw = Wro2 + lrow * 128 + quad * 8;
        for (int kk = 0; kk < 4; ++kk) {
            short8 a0 = *(const short8*)(ap + kk * 32);
            short8 a1 = *(const short8*)(ap + 16 * 136 + kk * 32);
            short8 bv = *(const short8*)(bw + kk * 32);
            acc0 = MFMA(a0, bv, acc0, 0, 0, 0);
            acc1 = MFMA(a1, bv, acc1, 0, 0, 0);
        }
        int q = lrow;
        if (q < NCLS) {
            float bias = ro_b2g[q];
#pragma unroll
            for (int i = 0; i < 2; ++i) {
#pragma unroll
                for (int rr = 0; rr < 4; ++rr) {
                    int m = i * 16 + quad * 4 + rr;
                    float v = (i ? acc1[rr] : acc0[rr]) + bias;
                    if (m >= nr) v = 0.f;
                    pred[((size_t)(b * 32 + m)) * NCLS + q] = v;
                }
            }
        }
    }
}

// ---------------------------------------------------------------------------
extern "C" void kernel_launch(void* const* d_in, const int* in_sizes, int n_in,
                              void* d_out, int out_size, void* d_ws, size_t ws_size,
                              hipStream_t stream)
{
    const float* nodes = (const float*)d_in[0];
    const float* pos   = (const float*)d_in[1];
    const int*   nrec  = (const int*)d_in[2];
    const float* w1    = (const float*)d_in[3];
    const float* b1    = (const float*)d_in[4];
    const float* w2    = (const float*)d_in[5];
    const float* b2    = (const float*)d_in[6];
    const float* msg_w = (const float*)d_in[7];
    const float* msg_b = (const float*)d_in[8];
    const float* w_ih  = (const float*)d_in[9];
    const float* w_hh  = (const float*)d_in[10];
    const float* b_ih  = (const float*)d_in[11];
    const float* b_hh  = (const float*)d_in[12];
    const float* ro_w1 = (const float*)d_in[13];
    const float* ro_b1 = (const float*)d_in[14];
    const float* ro_w2 = (const float*)d_in[15];
    const float* ro_b2 = (const float*)d_in[16];
    float* ws   = (float*)d_ws;
    float* pred = (float*)d_out;
    float* attout = pred + (size_t)N_G * M_N * NCLS;

    prep_kernel<<<256, 256, 0, stream>>>(w1, msg_w, w_ih, w_hh, ro_w1, ro_w2,
                                         b_ih, b_hh, ws);
    fused_kernel<<<N_G, 512, 0, stream>>>(nodes, pos, nrec, b1, w2, b2, msg_b,
                                          ro_b1, ro_b2, ws, attout, pred);
}

// Round 4
// 160.419 us; speedup vs baseline: 1.2818x; 1.2818x over previous
//
#include <hip/hip_runtime.h>
#include <math.h>

#define N_G   64
#define M_N   32
#define FEAT  256
#define POSD  6
#define D     262
#define MSG   128
#define NCLS  7

#define KA_S  424       // LDS buf row stride (shorts): [mv 128 | h 262 | pad]
#define KHW   288       // weight K window over h (262 -> 288)
#define KFULL 416       // full concat K
#define PSTR  320       // paL/pbL row stride (shorts), covers c16*4+64k up to 316

// packed weight sizes (shorts)
#define S_PROJ (528*288)
#define S_MSG  (128*288)
#define S_RZ   (544*416)
#define S_XN   (272*128)
#define S_HN   (272*288)
#define S_RO   (128*288)
#define S_RO2  (16*128)

// workspace float offsets
#define O_WPROJ 0u
#define O_WMSG  76032u
#define O_WRZ   94464u
#define O_WXN   207616u
#define O_WHN   225024u
#define O_WRO   264192u
#define O_WRO2  282624u
#define O_GB    283648u   // 1088 fp32 gate biases [br|bz|bxn|bhn] x 272

typedef __attribute__((ext_vector_type(8))) short short8;
typedef __attribute__((ext_vector_type(4))) short short4v;
typedef __attribute__((ext_vector_type(4))) float floatx4;

#define MFMA __builtin_amdgcn_mfma_f32_16x16x32_bf16

__device__ __forceinline__ short f2bf(float f) {
    union { float f; unsigned u; } v; v.f = f;
    unsigned r = v.u + 0x7FFF + ((v.u >> 16) & 1);   // RNE
    return (short)(r >> 16);
}
__device__ __forceinline__ float bf2f(short s) {
    union { float f; unsigned u; } v;
    v.u = ((unsigned)(unsigned short)s) << 16;
    return v.f;
}
__device__ __forceinline__ float sigf(float x) { return 1.f / (1.f + expf(-x)); }

// ---------------------------------------------------------------------------
// prep: pack all weights bf16 [n][k] (B^T) with padded/zeroed windows + biases
// ---------------------------------------------------------------------------
__global__ void prep_kernel(const float* __restrict__ w1, const float* __restrict__ msg_w,
                            const float* __restrict__ w_ih, const float* __restrict__ w_hh,
                            const float* __restrict__ ro_w1, const float* __restrict__ ro_w2,
                            const float* __restrict__ b_ih, const float* __restrict__ b_hh,
                            float* __restrict__ ws)
{
    short* wproj = (short*)(ws + O_WPROJ);
    short* wmsg  = (short*)(ws + O_WMSG);
    short* wrz   = (short*)(ws + O_WRZ);
    short* wxn   = (short*)(ws + O_WXN);
    short* whn   = (short*)(ws + O_WHN);
    short* wro   = (short*)(ws + O_WRO);
    short* wro2  = (short*)(ws + O_WRO2);
    float* gb    = ws + O_GB;
    const int TOT_S = S_PROJ + S_MSG + S_RZ + S_XN + S_HN + S_RO + S_RO2;
    const int TOTAL = TOT_S + 1088;
    for (int i = blockIdx.x * blockDim.x + threadIdx.x; i < TOTAL;
         i += gridDim.x * blockDim.x) {
        int idx = i;
        if (idx < S_PROJ) {                       // [528][288]
            int n = idx / 288, k = idx % 288;
            float v = 0.f;
            if (k < D && n < 524)
                v = (n < D) ? w1[n * 524 + k] : w1[(n - D) * 524 + D + k];
            wproj[idx] = f2bf(v);
            continue;
        }
        idx -= S_PROJ;
        if (idx < S_MSG) {                        // [128][288]
            int n = idx / 288, k = idx % 288;
            wmsg[idx] = f2bf(k < D ? msg_w[n * D + k] : 0.f);
            continue;
        }
        idx -= S_MSG;
        if (idx < S_RZ) {                         // [544][416]: rows 0..271 r, 272..543 z
            int g = idx / 416, k = idx % 416;
            int gi = (g < 272) ? 0 : 1;
            int d = g - gi * 272;
            float v = 0.f;
            if (d < D) {
                int row = gi * D + d;
                if (k < 128)            v = w_ih[row * MSG + k];
                else if (k < 128 + D)   v = w_hh[row * D + (k - 128)];
            }
            wrz[idx] = f2bf(v);
            continue;
        }
        idx -= S_RZ;
        if (idx < S_XN) {                         // [272][128]
            int d = idx / 128, k = idx % 128;
            wxn[idx] = f2bf(d < D ? w_ih[(2 * D + d) * MSG + k] : 0.f);
            continue;
        }
        idx -= S_XN;
        if (idx < S_HN) {                         // [272][288]
            int d = idx / 288, k = idx % 288;
            whn[idx] = f2bf((d < D && k < D) ? w_hh[(2 * D + d) * D + k] : 0.f);
            continue;
        }
        idx -= S_HN;
        if (idx < S_RO) {                         // [128][288]
            int n = idx / 288, k = idx % 288;
            wro[idx] = f2bf(k < D ? ro_w1[n * D + k] : 0.f);
            continue;
        }
        idx -= S_RO;
        if (idx < S_RO2) {                        // [16][128]
            int n = idx / 128, k = idx % 128;
            wro2[idx] = f2bf(n < NCLS ? ro_w2[n * MSG + k] : 0.f);
            continue;
        }
        idx -= S_RO2;
        {                                          // gate biases [4][272]
            int seg = idx / 272, d = idx % 272;
            float v = 0.f;
            if (d < D) {
                if (seg == 0)      v = b_ih[d] + b_hh[d];
                else if (seg == 1) v = b_ih[D + d] + b_hh[D + d];
                else if (seg == 2) v = b_ih[2 * D + d];
                else               v = b_hh[2 * D + d];
            }
            gb[idx] = v;
        }
    }
}

// ---------------------------------------------------------------------------
// fused: one block per graph; full forward in LDS
// ---------------------------------------------------------------------------
__global__ __launch_bounds__(512, 2) void fused_kernel(
    const float* __restrict__ nodes, const float* __restrict__ pos,
    const int* __restrict__ nrec_g,
    const float* __restrict__ b1g, const float* __restrict__ w2g,
    const float* __restrict__ b2g, const float* __restrict__ msg_bg,
    const float* __restrict__ ro_b1g, const float* __restrict__ ro_b2g,
    const float* __restrict__ ws,
    float* __restrict__ att_out, float* __restrict__ pred)
{
    const short* Wproj = (const short*)(ws + O_WPROJ);
    const short* Wmsg  = (const short*)(ws + O_WMSG);
    const short* Wrz   = (const short*)(ws + O_WRZ);
    const short* Wxn   = (const short*)(ws + O_WXN);
    const short* Whn   = (const short*)(ws + O_WHN);
    const short* Wro   = (const short*)(ws + O_WRO);
    const short* Wro2  = (const short*)(ws + O_WRO2);
    const float* gb    = ws + O_GB;

    __shared__ __align__(16) short bufA[32 * KA_S];
    __shared__ __align__(16) short bufB[32 * KA_S];
    __shared__ __align__(16) short paL[32 * PSTR];
    __shared__ __align__(16) short pbL[32 * PSTR];
    __shared__ __align__(16) short attL[32 * 40];   // bf16 A-layout for mix
    __shared__ __align__(16) short msgT[128 * 40];  // bf16 B^T layout for mix
    __shared__ __align__(16) short hidL[32 * 136];
    __shared__ __align__(16) float b1L[PSTR], w2L[PSTR];

    const int b = blockIdx.x;
    const int tid = threadIdx.x;
    const int wave = tid >> 6, lane = tid & 63;
    const int quad = lane >> 4, lrow = lane & 15;
    const int nr = nrec_g[b];

    // ---- P0: load h0 bf16, zero pads, stage padded b1/w2 ----
    for (int idx = tid; idx < 32 * 64; idx += 512) {          // nodes (float4)
        int w = idx >> 6, c4 = idx & 63;
        floatx4 v = *(const floatx4*)(nodes + ((size_t)(b * 32 + w)) * FEAT + c4 * 4);
        short4v s; s[0] = f2bf(v[0]); s[1] = f2bf(v[1]); s[2] = f2bf(v[2]); s[3] = f2bf(v[3]);
        *(short4v*)(bufA + w * KA_S + 128 + c4 * 4) = s;
    }
    for (int idx = tid; idx < 32 * POSD; idx += 512) {        // pos
        int w = idx / POSD, c = idx % POSD;
        bufA[w * KA_S + 128 + FEAT + c] = f2bf(pos[((size_t)(b * 32 + w)) * POSD + c]);
    }
    for (int idx = tid; idx < 32 * 34; idx += 512) {          // col pads 390..423
        int w = idx / 34, c = idx % 34;
        bufA[w * KA_S + 390 + c] = 0;
        bufB[w * KA_S + 390 + c] = 0;
    }
    for (int idx = tid; idx < 32 * (PSTR - D); idx += 512) {  // pa/pb pads 262..319
        int w = idx / (PSTR - D), c = idx % (PSTR - D);
        paL[w * PSTR + D + c] = 0;
        pbL[w * PSTR + D + c] = 0;
    }
    for (int d = tid; d < PSTR; d += 512) {
        b1L[d] = (d < D) ? b1g[d] : 0.f;
        w2L[d] = (d < D) ? w2g[d] : 0.f;
    }
    __syncthreads();

    // ---- P1: proj = h0 @ Wproj^T (528 cols) -> paL/pbL bf16 ----
    for (int s = wave; s < 33; s += 8) {
        floatx4 acc0 = {}, acc1 = {};
        const short* bw = Wproj + (s * 16 + lrow) * KHW + quad * 8;
        const short* ap = bufA + lrow * KA_S + 128 + quad * 8;
        for (int kk = 0; kk < 9; ++kk) {
            short8 a0 = *(const short8*)(ap + kk * 32);
            short8 a1 = *(const short8*)(ap + 16 * KA_S + kk * 32);
            short8 bv = *(const short8*)(bw + kk * 32);
            acc0 = MFMA(a0, bv, acc0, 0, 0, 0);
            acc1 = MFMA(a1, bv, acc1, 0, 0, 0);
        }
        int col = s * 16 + lrow;
#pragma unroll
        for (int rr = 0; rr < 4; ++rr) {
            int r0 = quad * 4 + rr;
            if (col < D) {
                paL[r0 * PSTR + col] = f2bf(acc0[rr]);
                paL[(r0 + 16) * PSTR + col] = f2bf(acc1[rr]);
            } else if (col < 2 * D) {
                pbL[r0 * PSTR + (col - D)] = f2bf(acc0[rr]);
                pbL[(r0 + 16) * PSTR + (col - D)] = f2bf(acc1[rr]);
            }
        }
    }
    __syncthreads();

    // ---- P2: attention (16-lane group per receiver i) ----
    {
        const int grp = tid >> 4;      // i = grp (0..31)
        const int c16 = tid & 15;
        const float b2v = b2g[0];
        float pav[5][4], b1v[5][4], w2v[5][4];
#pragma unroll
        for (int k = 0; k < 5; ++k) {
            int dbase = c16 * 4 + 64 * k;
            short4v p = *(const short4v*)(paL + grp * PSTR + dbase);
            floatx4 bb = *(const floatx4*)(b1L + dbase);
            floatx4 ww = *(const floatx4*)(w2L + dbase);
#pragma unroll
            for (int e = 0; e < 4; ++e) {
                pav[k][e] = bf2f(p[e]); b1v[k][e] = bb[e]; w2v[k][e] = ww[e];
            }
        }
        // c0 = invalid-pair logit
        float p0 = 0.f;
#pragma unroll
        for (int k = 0; k < 5; ++k)
#pragma unroll
            for (int e = 0; e < 4; ++e)
                p0 += fmaxf(b1v[k][e], 0.f) * w2v[k][e];
        p0 += __shfl_down(p0, 8, 16); p0 += __shfl_down(p0, 4, 16);
        p0 += __shfl_down(p0, 2, 16); p0 += __shfl_down(p0, 1, 16);
        float c0 = sigf(p0 + b2v);
        const bool vi = grp < nr;
        for (int j = 0; j < 32; ++j) {
            float a;
            if (j < nr && vi) {
                const short* pb = pbL + j * PSTR + c16 * 4;
                float s = 0.f;
#pragma unroll
                for (int k = 0; k < 5; ++k) {
                    short4v q = *(const short4v*)(pb + 64 * k);
#pragma unroll
                    for (int e = 0; e < 4; ++e) {
                        float v = pav[k][e] + bf2f(q[e]) + b1v[k][e];
                        s += fmaxf(v, 0.f) * w2v[k][e];
                    }
                }
                s += __shfl_down(s, 8, 16); s += __shfl_down(s, 4, 16);
                s += __shfl_down(s, 2, 16); s += __shfl_down(s, 1, 16);
                a = sigf(s + b2v);
            } else {
                a = c0;
            }
            if (c16 == 0) {
                att_out[((size_t)(b * 32 + grp)) * 32 + j] = a;
                attL[grp * 40 + j] = f2bf((j < nr) ? a : 0.f);
            }
        }
    }
    __syncthreads();

    // ---- two message-passing rounds ----
    for (int rnd = 0; rnd < 2; ++rnd) {
        short* src = rnd ? bufB : bufA;
        short* dst = rnd ? bufA : bufB;

        // msg = h @ Wmsg^T + msg_b -> msgT bf16 (transposed: [col][w])
        {
            int s = wave;
            floatx4 acc0 = {}, acc1 = {};
            const short* bw = Wmsg + (s * 16 + lrow) * KHW + quad * 8;
            const short* ap = src + lrow * KA_S + 128 + quad * 8;
            for (int kk = 0; kk < 9; ++kk) {
                short8 a0 = *(const short8*)(ap + kk * 32);
                short8 a1 = *(const short8*)(ap + 16 * KA_S + kk * 32);
                short8 bv = *(const short8*)(bw + kk * 32);
                acc0 = MFMA(a0, bv, acc0, 0, 0, 0);
                acc1 = MFMA(a1, bv, acc1, 0, 0, 0);
            }
            int col = s * 16 + lrow;
            float bias = msg_bg[col];
#pragma unroll
            for (int rr = 0; rr < 4; ++rr) {
                msgT[col * 40 + quad * 4 + rr] = f2bf(acc0[rr] + bias);
                msgT[col * 40 + 16 + quad * 4 + rr] = f2bf(acc1[rr] + bias);
            }
        }
        __syncthreads();

        // mix via MFMA: mv = attL(32x32) @ msg -> bf16 src cols 0..127
        {
            int mi = wave & 1, ng = wave >> 1;
            short8 afrag = *(const short8*)(attL + (mi * 16 + lrow) * 40 + quad * 8);
            floatx4 acc0 = {}, acc1 = {};
            short8 bf0 = *(const short8*)(msgT + (ng * 32 + lrow) * 40 + quad * 8);
            short8 bf1 = *(const short8*)(msgT + (ng * 32 + 16 + lrow) * 40 + quad * 8);
            acc0 = MFMA(afrag, bf0, acc0, 0, 0, 0);
            acc1 = MFMA(afrag, bf1, acc1, 0, 0, 0);
#pragma unroll
            for (int rr = 0; rr < 4; ++rr) {
                int m = mi * 16 + quad * 4 + rr;
                src[m * KA_S + ng * 32 + lrow] = f2bf(acc0[rr]);
                src[m * KA_S + ng * 32 + 16 + lrow] = f2bf(acc1[rr]);
            }
        }
        __syncthreads();

        // GRU: fused [gx|gh] GEMM + elementwise, writes dst h-cols
        for (int s = wave; s < 17; s += 8) {
            floatx4 aR0 = {}, aR1 = {}, aZ0 = {}, aZ1 = {};
            floatx4 aN0 = {}, aN1 = {}, aH0 = {}, aH1 = {};
            const short* ap  = src + lrow * KA_S + quad * 8;
            const short* bpr = Wrz + (s * 16 + lrow) * KFULL + quad * 8;
            const short* bpz = Wrz + (272 + s * 16 + lrow) * KFULL + quad * 8;
            const short* bpx = Wxn + (s * 16 + lrow) * 128 + quad * 8;
            const short* bph = Whn + (s * 16 + lrow) * KHW + quad * 8;
            for (int kk = 0; kk < 13; ++kk) {
                short8 a0 = *(const short8*)(ap + kk * 32);
                short8 a1 = *(const short8*)(ap + 16 * KA_S + kk * 32);
                short8 br = *(const short8*)(bpr + kk * 32);
                short8 bz = *(const short8*)(bpz + kk * 32);
                aR0 = MFMA(a0, br, aR0, 0, 0, 0);
                aR1 = MFMA(a1, br, aR1, 0, 0, 0);
                aZ0 = MFMA(a0, bz, aZ0, 0, 0, 0);
                aZ1 = MFMA(a1, bz, aZ1, 0, 0, 0);
                if (kk < 4) {
                    short8 bx = *(const short8*)(bpx + kk * 32);
                    aN0 = MFMA(a0, bx, aN0, 0, 0, 0);
                    aN1 = MFMA(a1, bx, aN1, 0, 0, 0);
                } else {
                    short8 bh = *(const short8*)(bph + (kk - 4) * 32);
                    aH0 = MFMA(a0, bh, aH0, 0, 0, 0);
                    aH1 = MFMA(a1, bh, aH1, 0, 0, 0);
                }
            }
            int d = s * 16 + lrow;
            if (d < D) {
                float bgr = gb[d], bgz = gb[272 + d];
                float bxv = gb[544 + d], bhv = gb[816 + d];
#pragma unroll
                for (int i = 0; i < 2; ++i) {
                    floatx4 vR = i ? aR1 : aR0, vZ = i ? aZ1 : aZ0;
                    floatx4 vN = i ? aN1 : aN0, vH = i ? aH1 : aH0;
#pragma unroll
                    for (int rr = 0; rr < 4; ++rr) {
                        int m = i * 16 + quad * 4 + rr;
                        float rg = sigf(vR[rr] + bgr);
                        float zg = sigf(vZ[rr] + bgz);
                        float cg = tanhf(vN[rr] + bxv + rg * (vH[rr] + bhv));
                        float hold = bf2f(src[m * KA_S + 128 + d]);
                        float hv = (1.f - zg) * cg + zg * hold;
                        if (m >= nr) hv = 0.f;
                        dst[m * KA_S + 128 + d] = f2bf(hv);
                    }
                }
            }
        }
        __syncthreads();
    }

    // ---- readout: hid = relu(h2 @ Wro^T + ro_b1), h2 in bufA ----
    {
        int s = wave;
        floatx4 acc0 = {}, acc1 = {};
        const short* bw = Wro + (s * 16 + lrow) * KHW + quad * 8;
        const short* ap = bufA + lrow * KA_S + 128 + quad * 8;
        for (int kk = 0; kk < 9; ++kk) {
            short8 a0 = *(const short8*)(ap + kk * 32);
            short8 a1 = *(const short8*)(ap + 16 * KA_S + kk * 32);
            short8 bv = *(const short8*)(bw + kk * 32);
            acc0 = MFMA(a0, bv, acc0, 0, 0, 0);
            acc1 = MFMA(a1, bv, acc1, 0, 0, 0);
        }
        int col = s * 16 + lrow;
        float bias = ro_b1g[col];
#pragma unroll
        for (int rr = 0; rr < 4; ++rr) {
            hidL[(quad * 4 + rr) * 136 + col] = f2bf(fmaxf(acc0[rr] + bias, 0.f));
            hidL[(16 + quad * 4 + rr) * 136 + col] = f2bf(fmaxf(acc1[rr] + bias, 0.f));
        }
    }
    __syncthreads();

    // ---- final: pred = hid @ ro_w2^T + ro_b2 (wave 0 only) ----
    if (wave == 0) {
        floatx4 acc0 = {}, acc1 = {};
        const short* ap = hidL + lrow * 136 + quad * 8;
        const short* bw = Wro2 + lrow * 128 + quad * 8;
        for (int kk = 0; kk < 4; ++kk) {
            short8 a0 = *(const short8*)(ap + kk * 32);
            short8 a1 = *(const short8*)(ap + 16 * 136 + kk * 32);
            short8 bv = *(const short8*)(bw + kk * 32);
            acc0 = MFMA(a0, bv, acc0, 0, 0, 0);
            acc1 = MFMA(a1, bv, acc1, 0, 0, 0);
        }
        int q = lrow;
        if (q < NCLS) {
            float bias = ro_b2g[q];
#pragma unroll
            for (int i = 0; i < 2; ++i) {
#pragma unroll
                for (int rr = 0; rr < 4; ++rr) {
                    int m = i * 16 + quad * 4 + rr;
                    float v = (i ? acc1[rr] : acc0[rr]) + bias;
                    if (m >= nr) v = 0.f;
                    pred[((size_t)(b * 32 + m)) * NCLS + q] = v;
                }
            }
        }
    }
}

// ---------------------------------------------------------------------------
extern "C" void kernel_launch(void* const* d_in, const int* in_sizes, int n_in,
                              void* d_out, int out_size, void* d_ws, size_t ws_size,
                              hipStream_t stream)
{
    const float* nodes = (const float*)d_in[0];
    const float* pos   = (const float*)d_in[1];
    const int*   nrec  = (const int*)d_in[2];
    const float* w1    = (const float*)d_in[3];
    const float* b1    = (const float*)d_in[4];
    const float* w2    = (const float*)d_in[5];
    const float* b2    = (const float*)d_in[6];
    const float* msg_w = (const float*)d_in[7];
    const float* msg_b = (const float*)d_in[8];
    const float* w_ih  = (const float*)d_in[9];
    const float* w_hh  = (const float*)d_in[10];
    const float* b_ih  = (const float*)d_in[11];
    const float* b_hh  = (const float*)d_in[12];
    const float* ro_w1 = (const float*)d_in[13];
    const float* ro_b1 = (const float*)d_in[14];
    const float* ro_w2 = (const float*)d_in[15];
    const float* ro_b2 = (const float*)d_in[16];
    float* ws   = (float*)d_ws;
    float* pred = (float*)d_out;
    float* attout = pred + (size_t)N_G * M_N * NCLS;

    prep_kernel<<<256, 256, 0, stream>>>(w1, msg_w, w_ih, w_hh, ro_w1, ro_w2,
                                         b_ih, b_hh, ws);
    fused_kernel<<<N_G, 512, 0, stream>>>(nodes, pos, nrec, b1, w2, b2, msg_b,
                                          ro_b1, ro_b2, ws, attout, pred);
}